// Round 3
// baseline (7611.576 us; speedup 1.0000x reference)
//
#include <hip/hip_runtime.h>
#include <stdint.h>

// ---------- problem constants ----------
#define B_   16
#define S_   128
#define H_   512
#define E_   512
#define V_   32000
#define G4_  2048   // 4*H

typedef _Float16 f16x8 __attribute__((ext_vector_type(8)));
typedef float    f32x4 __attribute__((ext_vector_type(4)));
typedef _Float16 h2v   __attribute__((ext_vector_type(2)));

// ---------- helpers ----------
static __device__ inline uint32_t pack_h2(float a, float b) {
  h2v h; h.x = (_Float16)a; h.y = (_Float16)b;
  return __builtin_bit_cast(uint32_t, h);
}
static __device__ inline float dot2_acc(uint32_t w, uint32_t h, float acc) {
#if __has_builtin(__builtin_amdgcn_fdot2)
  return __builtin_amdgcn_fdot2(__builtin_bit_cast(h2v, w),
                                __builtin_bit_cast(h2v, h), acc, false);
#else
  h2v wv = __builtin_bit_cast(h2v, w);
  h2v hv = __builtin_bit_cast(h2v, h);
  return acc + (float)wv.x * (float)hv.x + (float)wv.y * (float)hv.y;
#endif
}
static __device__ inline float sigm(float x) { return 1.f / (1.f + __expf(-x)); }
static __device__ inline float tanh_c(float x) {
  float xc = fminf(fmaxf(x, -15.f), 15.f);
  float e = __expf(-2.f * xc);
  return (1.f - e) / (1.f + e);
}
static __device__ inline void gld_lds16(const void* g, void* l) {
  __builtin_amdgcn_global_load_lds(
      (__attribute__((address_space(1))) void*)(void*)g,
      (__attribute__((address_space(3))) void*)l, 16, 0, 0);
}

// ---------- prep kernels ----------
__global__ __launch_bounds__(256) void cvt_f32_f16(const float* __restrict__ in,
                                                   unsigned short* __restrict__ out,
                                                   int n4) {
  int i = blockIdx.x * 256 + threadIdx.x;
  if (i >= n4) return;
  float4 v = ((const float4*)in)[i];
  uint2 o;
  o.x = pack_h2(v.x, v.y);
  o.y = pack_h2(v.z, v.w);
  ((uint2*)out)[i] = o;
}

// A_e[m][k] f16, row m = s*16+b, gathered from emb[x[b][s]]
__global__ __launch_bounds__(256) void gather_embed(const int* __restrict__ x,
                                                    const float* __restrict__ emb,
                                                    uint32_t* __restrict__ Ae) {
  int m = blockIdx.x, t = threadIdx.x;
  int s = m >> 4, b = m & 15;
  int xv = x[b * S_ + s];
  float2 v = ((const float2*)(emb + (size_t)xv * E_))[t];
  Ae[(size_t)m * (E_ / 2) + t] = pack_h2(v.x, v.y);
}

// Whh packed half2, per-thread-contiguous layout (512-thread lstm, 4 rows/thread):
// out[tix*1024 + k2*4 + r] = pack(W_hh[tix*4+r][2k2], W_hh[tix*4+r][2k2+1])
__global__ __launch_bounds__(256) void pack_whh(const float* __restrict__ whh,
                                                uint32_t* __restrict__ out) {
  int idx = blockIdx.x * 256 + threadIdx.x;     // 0 .. 524287
  int tix = idx >> 10;        // 0..511
  int k2  = (idx >> 2) & 255; // 0..255
  int r   = idx & 3;          // 0..3
  int j   = tix * 4 + r;      // gate row
  float a = whh[(size_t)j * H_ + 2 * k2];
  float b = whh[(size_t)j * H_ + 2 * k2 + 1];
  out[idx] = pack_h2(a, b);
}

// ---------- f16 MFMA GEMM: C[M][N] = A[M][K] * Bt[N][K]^T + bias ----------
__global__ __launch_bounds__(256, 2) void gemm_bt(
    const unsigned short* __restrict__ A, const unsigned short* __restrict__ Bt,
    float* __restrict__ C, const float* __restrict__ bias_a,
    const float* __restrict__ bias_b, int M, int N, int K) {
  __shared__ unsigned short As[128 * 32];
  __shared__ unsigned short Bs[128 * 32];
  const int tid = threadIdx.x;
  const int bn = blockIdx.x, bm = blockIdx.y;
  const int lane = tid & 63, wid = tid >> 6;
  const int wr = wid >> 1, wc = wid & 1;
  const int fr = lane & 15, kg = lane >> 4;

  f32x4 acc[4][4] = {};

  const unsigned short* ag = A + (size_t)(bm * 128 + (tid >> 2)) * K + (tid & 3) * 8;
  const unsigned short* bg = Bt + (size_t)(bn * 128 + (tid >> 2)) * K + (tid & 3) * 8;
  char* asl = (char*)As + tid * 16;
  char* bsl = (char*)Bs + tid * 16;

  for (int k0 = 0; k0 < K; k0 += 32) {
    __syncthreads();
    gld_lds16(ag + k0, asl);
    gld_lds16(ag + (size_t)64 * K + k0, asl + 4096);
    gld_lds16(bg + k0, bsl);
    gld_lds16(bg + (size_t)64 * K + k0, bsl + 4096);
    __syncthreads();
    f16x8 aF[4], bF[4];
#pragma unroll
    for (int i = 0; i < 4; ++i)
      aF[i] = *(const f16x8*)&As[(wr * 64 + i * 16 + fr) * 32 + kg * 8];
#pragma unroll
    for (int j = 0; j < 4; ++j)
      bF[j] = *(const f16x8*)&Bs[(wc * 64 + j * 16 + fr) * 32 + kg * 8];
#pragma unroll
    for (int i = 0; i < 4; ++i)
#pragma unroll
      for (int j = 0; j < 4; ++j)
        acc[i][j] = __builtin_amdgcn_mfma_f32_16x16x32_f16(aF[i], bF[j], acc[i][j], 0, 0, 0);
  }

  const int r4 = kg * 4;
#pragma unroll
  for (int j = 0; j < 4; ++j) {
    int col = bn * 128 + wc * 64 + j * 16 + fr;
    float bs = 0.f;
    if (bias_a) bs += bias_a[col];
    if (bias_b) bs += bias_b[col];
#pragma unroll
    for (int i = 0; i < 4; ++i) {
      int row = bm * 128 + wr * 64 + i * 16 + r4;
#pragma unroll
      for (int g = 0; g < 4; ++g)
        C[(size_t)(row + g) * N + col] = acc[i][j][g] + bs;
    }
  }
}

// ---------- LSTM recurrence: 1 block (512 thr) per batch element ----------
// thread t: dot-phase computes gate rows 4t..4t+3; gate-phase owns hidden unit t.
__global__ __launch_bounds__(512, 1) void lstm_kernel(
    const float* __restrict__ xg,        // [S][B][4H]
    const uint32_t* __restrict__ whh,    // per-thread-contiguous packed half2
    const float* __restrict__ z,         // [B][2H] : h0 | c0
    float* __restrict__ hs,              // [B*S][H], row = b*S + s
    float* __restrict__ hc) {            // [B][2H] : h | c  (d_out tail)
  const int b = blockIdx.x, t = threadIdx.x;
  __shared__ _Float16 hh[H_];           // current h, f16
  __shared__ float pre[G4_];            // gate pre-activations

  float c_reg = z[(size_t)b * 1024 + 512 + t];
  hh[t] = (_Float16)z[(size_t)b * 1024 + t];
  float h_reg = 0.f;
  __syncthreads();

  const uint4* wp = (const uint4*)(whh + (size_t)t * 1024);  // 4KB stream/thread
  const uint32_t* hp = (const uint32_t*)hh;
  for (int s = 0; s < S_; ++s) {
    const float4 xr = *(const float4*)(xg + ((size_t)s * 16 + b) * G4_ + t * 4);
    float a0 = xr.x, a1 = xr.y, a2 = xr.z, a3 = xr.w;
#pragma unroll 8
    for (int k2 = 0; k2 < 256; ++k2) {
      uint32_t hv = hp[k2];
      uint4 w = wp[k2];
      a0 = dot2_acc(w.x, hv, a0);
      a1 = dot2_acc(w.y, hv, a1);
      a2 = dot2_acc(w.z, hv, a2);
      a3 = dot2_acc(w.w, hv, a3);
    }
    *(float4*)(pre + t * 4) = make_float4(a0, a1, a2, a3);
    __syncthreads();
    float gi = pre[t], gf = pre[512 + t], gg = pre[1024 + t], go = pre[1536 + t];
    c_reg = sigm(gf) * c_reg + sigm(gi) * tanh_c(gg);
    h_reg = sigm(go) * tanh_c(c_reg);
    hh[t] = (_Float16)h_reg;
    hs[((size_t)b * S_ + s) * H_ + t] = h_reg;
    __syncthreads();
  }
  hc[(size_t)b * 1024 + t] = h_reg;
  hc[(size_t)b * 1024 + 512 + t] = c_reg;
}

// ---------- layernorm -> f16 A matrix ----------
__global__ __launch_bounds__(256) void ln_kernel(const float* __restrict__ hs,
                                                 const float* __restrict__ gamma,
                                                 const float* __restrict__ beta,
                                                 uint32_t* __restrict__ Aln) {
  int row = blockIdx.x * 4 + (threadIdx.x >> 6);
  int lane = threadIdx.x & 63;
  const float4* r = (const float4*)(hs + (size_t)row * H_ + lane * 8);
  float4 v0 = r[0], v1 = r[1];
  float s = v0.x + v0.y + v0.z + v0.w + v1.x + v1.y + v1.z + v1.w;
  float q = v0.x * v0.x + v0.y * v0.y + v0.z * v0.z + v0.w * v0.w +
            v1.x * v1.x + v1.y * v1.y + v1.z * v1.z + v1.w * v1.w;
#pragma unroll
  for (int off = 32; off > 0; off >>= 1) {
    s += __shfl_xor(s, off);
    q += __shfl_xor(q, off);
  }
  float mu = s * (1.f / 512.f);
  float var = q * (1.f / 512.f) - mu * mu;
  float rstd = rsqrtf(var + 1e-5f);
  const float4* gp = (const float4*)(gamma + lane * 8);
  const float4* bp = (const float4*)(beta + lane * 8);
  float4 g0 = gp[0], g1 = gp[1], be0 = bp[0], be1 = bp[1];
  float y0 = (v0.x - mu) * rstd * g0.x + be0.x;
  float y1 = (v0.y - mu) * rstd * g0.y + be0.y;
  float y2 = (v0.z - mu) * rstd * g0.z + be0.z;
  float y3 = (v0.w - mu) * rstd * g0.w + be0.w;
  float y4 = (v1.x - mu) * rstd * g1.x + be1.x;
  float y5 = (v1.y - mu) * rstd * g1.y + be1.y;
  float y6 = (v1.z - mu) * rstd * g1.z + be1.z;
  float y7 = (v1.w - mu) * rstd * g1.w + be1.w;
  uint4 o = make_uint4(pack_h2(y0, y1), pack_h2(y2, y3), pack_h2(y4, y5), pack_h2(y6, y7));
  ((uint4*)Aln)[(size_t)row * 64 + lane] = o;
}

// ---------- launch ----------
extern "C" void kernel_launch(void* const* d_in, const int* in_sizes, int n_in,
                              void* d_out, int out_size, void* d_ws, size_t ws_size,
                              hipStream_t stream) {
  const int*   x    = (const int*)d_in[0];
  const float* z    = (const float*)d_in[1];
  const float* emb  = (const float*)d_in[2];
  const float* W_ih = (const float*)d_in[3];
  const float* W_hh = (const float*)d_in[4];
  const float* b_ih = (const float*)d_in[5];
  const float* b_hh = (const float*)d_in[6];
  const float* ln_g = (const float*)d_in[7];
  const float* ln_b = (const float*)d_in[8];
  const float* fc_W = (const float*)d_in[9];
  const float* fc_b = (const float*)d_in[10];
  float* out = (float*)d_out;

  char* ws = (char*)d_ws;
  unsigned short* Ae  = (unsigned short*)(ws + 0);         //  2,097,152 B
  unsigned short* Wih = (unsigned short*)(ws + 2097152);   //  2,097,152 B
  unsigned short* Wfc = (unsigned short*)(ws + 4194304);   // 32,768,000 B
  uint32_t*       Whh = (uint32_t*)(ws + 36962304);        //  2,097,152 B
  float*          xg  = (float*)(ws + 39059456);           // 16,777,216 B
  float*          hs  = (float*)(ws + 55836672);           //  4,194,304 B
  unsigned short* Aln = (unsigned short*)(ws + 60030976);  //  2,097,152 B  (total ~62.1MB)

  cvt_f32_f16<<<1024, 256, 0, stream>>>(W_ih, Wih, 262144);
  cvt_f32_f16<<<16000, 256, 0, stream>>>(fc_W, Wfc, 4096000);
  pack_whh<<<2048, 256, 0, stream>>>(W_hh, Whh);
  gather_embed<<<2048, 256, 0, stream>>>(x, emb, (uint32_t*)Ae);

  // xg[s*16+b][g] = e . W_ih[g] + b_ih[g] + b_hh[g]
  gemm_bt<<<dim3(16, 16), 256, 0, stream>>>(Ae, Wih, xg, b_ih, b_hh, 2048, 2048, 512);

  lstm_kernel<<<16, 512, 0, stream>>>(xg, Whh, z, hs, out + (size_t)65536000);

  ln_kernel<<<512, 256, 0, stream>>>(hs, ln_g, ln_b, (uint32_t*)Aln);

  // logits[b*128+s][v] = ln . fc_W[v] + fc_b[v]
  gemm_bt<<<dim3(250, 16), 256, 0, stream>>>(Aln, Wfc, out, fc_b, nullptr, 2048, 32000, 512);
}

// Round 5
// 1207.912 us; speedup vs baseline: 6.3014x; 6.3014x over previous
//
#include <hip/hip_runtime.h>
#include <stdint.h>

// ---------- problem constants ----------
#define B_   16
#define S_   128
#define H_   512
#define E_   512
#define V_   32000
#define G4_  2048   // 4*H

typedef _Float16 f16x8 __attribute__((ext_vector_type(8)));
typedef float    f32x4 __attribute__((ext_vector_type(4)));
typedef _Float16 h2v   __attribute__((ext_vector_type(2)));

// ---------- helpers ----------
static __device__ inline uint32_t pack_h2(float a, float b) {
  h2v h; h.x = (_Float16)a; h.y = (_Float16)b;
  return __builtin_bit_cast(uint32_t, h);
}
static __device__ inline unsigned short f16b(float a) {
  _Float16 h = (_Float16)a;
  return __builtin_bit_cast(unsigned short, h);
}
static __device__ inline float sigm(float x) { return 1.f / (1.f + __expf(-x)); }
static __device__ inline float tanh_c(float x) {
  float xc = fminf(fmaxf(x, -15.f), 15.f);
  float e = __expf(-2.f * xc);
  return (1.f - e) / (1.f + e);
}
static __device__ inline void gld_lds16(const void* g, void* l) {
  __builtin_amdgcn_global_load_lds(
      (__attribute__((address_space(1))) void*)(void*)g,
      (__attribute__((address_space(3))) void*)l, 16, 0, 0);
}

// ---------- prep kernels ----------
__global__ __launch_bounds__(256) void cvt_f32_f16(const float* __restrict__ in,
                                                   unsigned short* __restrict__ out,
                                                   int n4) {
  int i = blockIdx.x * 256 + threadIdx.x;
  if (i >= n4) return;
  float4 v = ((const float4*)in)[i];
  uint2 o;
  o.x = pack_h2(v.x, v.y);
  o.y = pack_h2(v.z, v.w);
  ((uint2*)out)[i] = o;
}

// A_e[m][k] f16, row m = s*16+b, gathered from emb[x[b][s]]
__global__ __launch_bounds__(256) void gather_embed(const int* __restrict__ x,
                                                    const float* __restrict__ emb,
                                                    uint32_t* __restrict__ Ae) {
  int m = blockIdx.x, t = threadIdx.x;
  int s = m >> 4, b = m & 15;
  int xv = x[b * S_ + s];
  float2 v = ((const float2*)(emb + (size_t)xv * E_))[t];
  Ae[(size_t)m * (E_ / 2) + t] = pack_h2(v.x, v.y);
}

// Whh -> MFMA A-fragment layout, f16.
// d8 = panel*2048 + km*64 + lane ; panel = blk*4+w ; km = kt*2+mt
// lane holds A[row = lane&15][k = (lane>>4)*8 + e] of m-tile (panel, mt).
// m-row r = uo*4 + g  (uo=r>>2, g=r&3); unit = blk*32 + (2w+mt)*4 + uo.
__global__ __launch_bounds__(256) void pack_whh_frag(const float* __restrict__ whh,
                                                     unsigned short* __restrict__ out) {
  int d8 = blockIdx.x * 256 + threadIdx.x;   // 0..131071
  int lane  = d8 & 63;
  int km    = (d8 >> 6) & 31;
  int kt    = km >> 1, mt = km & 1;
  int panel = d8 >> 11;                      // 0..63
  int blk = panel >> 2, w = panel & 3;
  int g  = lane & 3;
  int uo = (lane & 15) >> 2;
  int unit = blk * 32 + (2 * w + mt) * 4 + uo;
  int row  = g * 512 + unit;
  int kcol = kt * 32 + (lane >> 4) * 8;
  const float* src = whh + (size_t)row * H_ + kcol;
  float4 a = *(const float4*)(src);
  float4 b = *(const float4*)(src + 4);
  uint4 o;
  o.x = pack_h2(a.x, a.y); o.y = pack_h2(a.z, a.w);
  o.z = pack_h2(b.x, b.y); o.w = pack_h2(b.z, b.w);
  *(uint4*)(out + (size_t)d8 * 8) = o;
}

// hbuf parity0 <- f16(h0), zero barrier counter
__global__ __launch_bounds__(256) void init_h(const float* __restrict__ z,
                                              unsigned short* __restrict__ hbuf,
                                              unsigned int* __restrict__ cnt) {
  int i = blockIdx.x * 256 + threadIdx.x;    // 0..8191
  if (i == 0) *cnt = 0u;
  int b = i >> 9, u = i & 511;
  hbuf[i] = f16b(z[(size_t)b * 1024 + u]);
}

// ---------- f16 MFMA GEMM: C[M][N] = A[M][K] * Bt[N][K]^T + bias ----------
// PACK=1: write C into the lstm per-lane xg fragment layout instead of [M][N].
template <int PACK>
__global__ __launch_bounds__(256, 2) void gemm_bt(
    const unsigned short* __restrict__ A, const unsigned short* __restrict__ Bt,
    float* __restrict__ C, const float* __restrict__ bias_a,
    const float* __restrict__ bias_b, int M, int N, int K) {
  __shared__ unsigned short As[128 * 32];
  __shared__ unsigned short Bs[128 * 32];
  const int tid = threadIdx.x;
  const int bn = blockIdx.x, bm = blockIdx.y;
  const int lane = tid & 63, wid = tid >> 6;
  const int wr = wid >> 1, wc = wid & 1;
  const int fr = lane & 15, kg = lane >> 4;

  f32x4 acc[4][4] = {};

  const unsigned short* ag = A + (size_t)(bm * 128 + (tid >> 2)) * K + (tid & 3) * 8;
  const unsigned short* bg = Bt + (size_t)(bn * 128 + (tid >> 2)) * K + (tid & 3) * 8;
  char* asl = (char*)As + tid * 16;
  char* bsl = (char*)Bs + tid * 16;

  for (int k0 = 0; k0 < K; k0 += 32) {
    __syncthreads();
    gld_lds16(ag + k0, asl);
    gld_lds16(ag + (size_t)64 * K + k0, asl + 4096);
    gld_lds16(bg + k0, bsl);
    gld_lds16(bg + (size_t)64 * K + k0, bsl + 4096);
    __syncthreads();
    f16x8 aF[4], bF[4];
#pragma unroll
    for (int i = 0; i < 4; ++i)
      aF[i] = *(const f16x8*)&As[(wr * 64 + i * 16 + fr) * 32 + kg * 8];
#pragma unroll
    for (int j = 0; j < 4; ++j)
      bF[j] = *(const f16x8*)&Bs[(wc * 64 + j * 16 + fr) * 32 + kg * 8];
#pragma unroll
    for (int i = 0; i < 4; ++i)
#pragma unroll
      for (int j = 0; j < 4; ++j)
        acc[i][j] = __builtin_amdgcn_mfma_f32_16x16x32_f16(aF[i], bF[j], acc[i][j], 0, 0, 0);
  }

  const int r4 = kg * 4;
#pragma unroll
  for (int j = 0; j < 4; ++j) {
    int col = bn * 128 + wc * 64 + j * 16 + fr;
    float bs = 0.f;
    if (bias_a) bs += bias_a[col];
    if (bias_b) bs += bias_b[col];
#pragma unroll
    for (int i = 0; i < 4; ++i) {
      int row = bm * 128 + wr * 64 + i * 16 + r4;
#pragma unroll
      for (int g = 0; g < 4; ++g) {
        float val = acc[i][j][g] + bs;
        if constexpr (PACK == 0) {
          C[(size_t)(row + g) * N + col] = val;
        } else {
          int rr = row + g;              // = s*16 + batch
          int s = rr >> 4, batch = rr & 15;
          int g4 = col >> 9, unit = col & 511;
          int blk = unit >> 5, ul = unit & 31;
          int w = ul >> 3, mt = (ul >> 2) & 1, uo = ul & 3;
          int lane2 = (uo << 4) | batch;
          size_t d = ((((size_t)s * 16 + blk) * 4 + w) * 64 + lane2) * 8 + mt * 4 + g4;
          C[d] = val;
        }
      }
    }
  }
}

// ---------- LSTM recurrence: 16 blocks x 256 thr, weights VGPR-resident ----------
// Block owns 32 hidden units (128 gate rows) for ALL 16 batches.
// Per step: MFMA(W_regs, h_LDS) -> gates in-lane -> c,h update -> 1KB h-slice
// exchange via global ping-pong + one atomic barrier.
__global__ __launch_bounds__(256, 1) void lstm_coop(
    const float* __restrict__ xgp,          // packed per-lane gate pre-acts
    const unsigned short* __restrict__ whhp,// A-fragment packed weights
    const float* __restrict__ z,            // [B][2H] h0|c0
    unsigned short* __restrict__ hbuf,      // [2][16][512] f16 ping-pong
    unsigned int* __restrict__ cnt,         // barrier counter
    float* __restrict__ hs,                 // [B][S][H] f32
    float* __restrict__ hc) {               // [B][2H] h|c (d_out tail)
  const int blk = blockIdx.x, t = threadIdx.x;
  const int w = t >> 6, lane = t & 63;
  const int batch = lane & 15, kgl = lane >> 4;
  const int panel = blk * 4 + w;
  __shared__ alignas(16) unsigned short hlds[8192];   // 16KB swizzled h

  // resident weights: 32 fragments = 128 VGPRs
  f16x8 A[16][2];
  const unsigned short* wb = whhp + (size_t)panel * 16384 + lane * 8;
#pragma unroll
  for (int kt = 0; kt < 16; ++kt) {
#pragma unroll
    for (int mt = 0; mt < 2; ++mt)
      A[kt][mt] = *(const f16x8*)(wb + (kt * 2 + mt) * 512);
  }

  const int u0 = blk * 32 + (2 * w) * 4 + (lane >> 4);
  const int u1 = u0 + 4;
  float c0 = z[(size_t)batch * 1024 + 512 + u0];
  float c1 = z[(size_t)batch * 1024 + 512 + u1];
  float h0f = 0.f, h1f = 0.f;

  // staging map: thread copies h[sb][sk..sk+32)
  const int sb = t >> 4, sk = (t & 15) * 32;
  const unsigned int sX = (unsigned)(sb & 7) << 4;
  const unsigned int rX = (unsigned)(batch & 7) << 4;
  const unsigned int rbase = batch * 1024 + kgl * 16;
  char* lb = (char*)hlds;

#pragma unroll 1
  for (int s = 0; s < S_; ++s) {
    // ---- stage h (written at step s-1, protected by barrier s-1) ----
    const unsigned short* hsrc = hbuf + (s & 1) * 8192 + sb * 512 + sk;
    uint4 g0 = *(const uint4*)(hsrc);
    uint4 g1 = *(const uint4*)(hsrc + 8);
    uint4 g2 = *(const uint4*)(hsrc + 16);
    uint4 g3 = *(const uint4*)(hsrc + 24);
    unsigned int wbase = sb * 1024 + sk * 2;
    *(uint4*)(lb + ((wbase +  0) ^ sX)) = g0;
    *(uint4*)(lb + ((wbase + 16) ^ sX)) = g1;
    *(uint4*)(lb + ((wbase + 32) ^ sX)) = g2;
    *(uint4*)(lb + ((wbase + 48) ^ sX)) = g3;
    __syncthreads();

    // ---- xg pre-acts (independent of barrier) ----
    const float* xp = xgp + (((size_t)s * 16 + blk) * 4 + w) * 512 + lane * 8;
    float4 x0 = *(const float4*)(xp);
    float4 x1 = *(const float4*)(xp + 4);

    // ---- MFMA: C(128x16) = W_slice @ h^T ----
    f32x4 acc0 = {}, acc1 = {};
#pragma unroll
    for (int kt = 0; kt < 16; ++kt) {
      f16x8 Bf = *(const f16x8*)(lb + ((rbase + kt * 64) ^ rX));
      acc0 = __builtin_amdgcn_mfma_f32_16x16x32_f16(A[kt][0], Bf, acc0, 0, 0, 0);
      acc1 = __builtin_amdgcn_mfma_f32_16x16x32_f16(A[kt][1], Bf, acc1, 0, 0, 0);
    }

    // ---- gates (i,f,g,o in-lane) ----
    float gi0 = acc0[0] + x0.x, gf0 = acc0[1] + x0.y, gg0 = acc0[2] + x0.z, go0 = acc0[3] + x0.w;
    float gi1 = acc1[0] + x1.x, gf1 = acc1[1] + x1.y, gg1 = acc1[2] + x1.z, go1 = acc1[3] + x1.w;
    c0 = sigm(gf0) * c0 + sigm(gi0) * tanh_c(gg0);
    h0f = sigm(go0) * tanh_c(c0);
    c1 = sigm(gf1) * c1 + sigm(gi1) * tanh_c(gg1);
    h1f = sigm(go1) * tanh_c(c1);

    // ---- publish h slice + hs output ----
    unsigned short* hdst = hbuf + ((s + 1) & 1) * 8192 + batch * 512;
    hdst[u0] = f16b(h0f);
    hdst[u1] = f16b(h1f);
    float* hr = hs + ((size_t)batch * S_ + s) * H_;
    hr[u0] = h0f;
    hr[u1] = h1f;

    // ---- barrier ----
    __threadfence();
    __syncthreads();
    if (t == 0) {
      atomicAdd(cnt, 1u);
      unsigned int target = 16u * (unsigned)(s + 1);
      while (__hip_atomic_load(cnt, __ATOMIC_RELAXED, __HIP_MEMORY_SCOPE_AGENT) < target)
        __builtin_amdgcn_s_sleep(2);
    }
    __syncthreads();
    __threadfence();
  }

  hc[(size_t)batch * 1024 + u0] = h0f;
  hc[(size_t)batch * 1024 + u1] = h1f;
  hc[(size_t)batch * 1024 + 512 + u0] = c0;
  hc[(size_t)batch * 1024 + 512 + u1] = c1;
}

// ---------- layernorm -> f16 A matrix ----------
__global__ __launch_bounds__(256) void ln_kernel(const float* __restrict__ hs,
                                                 const float* __restrict__ gamma,
                                                 const float* __restrict__ beta,
                                                 uint32_t* __restrict__ Aln) {
  int row = blockIdx.x * 4 + (threadIdx.x >> 6);
  int lane = threadIdx.x & 63;
  const float4* r = (const float4*)(hs + (size_t)row * H_ + lane * 8);
  float4 v0 = r[0], v1 = r[1];
  float s = v0.x + v0.y + v0.z + v0.w + v1.x + v1.y + v1.z + v1.w;
  float q = v0.x * v0.x + v0.y * v0.y + v0.z * v0.z + v0.w * v0.w +
            v1.x * v1.x + v1.y * v1.y + v1.z * v1.z + v1.w * v1.w;
#pragma unroll
  for (int off = 32; off > 0; off >>= 1) {
    s += __shfl_xor(s, off);
    q += __shfl_xor(q, off);
  }
  float mu = s * (1.f / 512.f);
  float var = q * (1.f / 512.f) - mu * mu;
  float rstd = rsqrtf(var + 1e-5f);
  const float4* gp = (const float4*)(gamma + lane * 8);
  const float4* bp = (const float4*)(beta + lane * 8);
  float4 g0 = gp[0], g1 = gp[1], be0 = bp[0], be1 = bp[1];
  float y0 = (v0.x - mu) * rstd * g0.x + be0.x;
  float y1 = (v0.y - mu) * rstd * g0.y + be0.y;
  float y2 = (v0.z - mu) * rstd * g0.z + be0.z;
  float y3 = (v0.w - mu) * rstd * g0.w + be0.w;
  float y4 = (v1.x - mu) * rstd * g1.x + be1.x;
  float y5 = (v1.y - mu) * rstd * g1.y + be1.y;
  float y6 = (v1.z - mu) * rstd * g1.z + be1.z;
  float y7 = (v1.w - mu) * rstd * g1.w + be1.w;
  uint4 o = make_uint4(pack_h2(y0, y1), pack_h2(y2, y3), pack_h2(y4, y5), pack_h2(y6, y7));
  ((uint4*)Aln)[(size_t)row * 64 + lane] = o;
}

// ---------- launch ----------
extern "C" void kernel_launch(void* const* d_in, const int* in_sizes, int n_in,
                              void* d_out, int out_size, void* d_ws, size_t ws_size,
                              hipStream_t stream) {
  const int*   x    = (const int*)d_in[0];
  const float* z    = (const float*)d_in[1];
  const float* emb  = (const float*)d_in[2];
  const float* W_ih = (const float*)d_in[3];
  const float* W_hh = (const float*)d_in[4];
  const float* b_ih = (const float*)d_in[5];
  const float* b_hh = (const float*)d_in[6];
  const float* ln_g = (const float*)d_in[7];
  const float* ln_b = (const float*)d_in[8];
  const float* fc_W = (const float*)d_in[9];
  const float* fc_b = (const float*)d_in[10];
  float* out = (float*)d_out;

  char* ws = (char*)d_ws;
  unsigned short* Ae   = (unsigned short*)(ws + 0);         //  2,097,152 B (reused for hbuf)
  unsigned short* Wih  = (unsigned short*)(ws + 2097152);   //  2,097,152 B
  unsigned short* Wfc  = (unsigned short*)(ws + 4194304);   // 32,768,000 B
  unsigned short* Whhp = (unsigned short*)(ws + 36962304);  //  2,097,152 B
  float*          xgp  = (float*)(ws + 39059456);           // 16,777,216 B
  float*          hs   = (float*)(ws + 55836672);           //  4,194,304 B
  unsigned short* Aln  = (unsigned short*)(ws + 60030976);  //  2,097,152 B (ends 62,128,128)
  // hbuf + cnt overlap the Ae region (Ae is dead after the xg GEMM)
  unsigned short* hbuf = (unsigned short*)(ws + 0);         // 32,768 B
  unsigned int*   cnt  = (unsigned int*)(ws + 32768);       // 4 B

  cvt_f32_f16<<<1024, 256, 0, stream>>>(W_ih, Wih, 262144);
  cvt_f32_f16<<<16000, 256, 0, stream>>>(fc_W, Wfc, 4096000);
  pack_whh_frag<<<512, 256, 0, stream>>>(W_hh, Whhp);
  gather_embed<<<2048, 256, 0, stream>>>(x, emb, (uint32_t*)Ae);

  // xg packed: xgp[lane-fragment layout] = e . W_ih[g] + b_ih + b_hh
  gemm_bt<1><<<dim3(16, 16), 256, 0, stream>>>(Ae, Wih, xgp, b_ih, b_hh, 2048, 2048, 512);

  init_h<<<32, 256, 0, stream>>>(z, hbuf, cnt);
  lstm_coop<<<16, 256, 0, stream>>>(xgp, Whhp, z, hbuf, cnt, hs, out + (size_t)65536000);

  ln_kernel<<<512, 256, 0, stream>>>(hs, ln_g, ln_b, (uint32_t*)Aln);

  // logits[b*128+s][v] = ln . fc_W[v] + fc_b
  gemm_bt<0><<<dim3(250, 16), 256, 0, stream>>>(Aln, Wfc, out, fc_b, nullptr, 2048, 32000, 512);
}

// Round 7
// 913.839 us; speedup vs baseline: 8.3292x; 1.3218x over previous
//
#include <hip/hip_runtime.h>
#include <stdint.h>

// ---------- problem constants ----------
#define B_   16
#define S_   128
#define H_   512
#define E_   512
#define V_   32000
#define G4_  2048   // 4*H

typedef _Float16 f16x8 __attribute__((ext_vector_type(8)));
typedef float    f32x4 __attribute__((ext_vector_type(4)));
typedef _Float16 h2v   __attribute__((ext_vector_type(2)));
typedef uint32_t u32x4 __attribute__((ext_vector_type(4)));

// ---------- helpers ----------
static __device__ inline uint32_t pack_h2(float a, float b) {
  h2v h; h.x = (_Float16)a; h.y = (_Float16)b;
  return __builtin_bit_cast(uint32_t, h);
}
static __device__ inline unsigned short f16b(float a) {
  _Float16 h = (_Float16)a;
  return __builtin_bit_cast(unsigned short, h);
}
static __device__ inline float sigm(float x) { return 1.f / (1.f + __expf(-x)); }
static __device__ inline float tanh_c(float x) {
  float xc = fminf(fmaxf(x, -15.f), 15.f);
  float e = __expf(-2.f * xc);
  return (1.f - e) / (1.f + e);
}
static __device__ inline void gld_lds16(const void* g, void* l) {
  __builtin_amdgcn_global_load_lds(
      (__attribute__((address_space(1))) void*)(void*)g,
      (__attribute__((address_space(3))) void*)l, 16, 0, 0);
}

// ---------- prep kernels ----------
__global__ __launch_bounds__(256) void cvt_f32_f16(const float* __restrict__ in,
                                                   unsigned short* __restrict__ out,
                                                   int n4) {
  int i = blockIdx.x * 256 + threadIdx.x;
  if (i >= n4) return;
  float4 v = ((const float4*)in)[i];
  uint2 o;
  o.x = pack_h2(v.x, v.y);
  o.y = pack_h2(v.z, v.w);
  ((uint2*)out)[i] = o;
}

// A_e[m][k] f16, row m = s*16+b, gathered from emb[x[b][s]]
__global__ __launch_bounds__(256) void gather_embed(const int* __restrict__ x,
                                                    const float* __restrict__ emb,
                                                    uint32_t* __restrict__ Ae) {
  int m = blockIdx.x, t = threadIdx.x;
  int s = m >> 4, b = m & 15;
  int xv = x[b * S_ + s];
  float2 v = ((const float2*)(emb + (size_t)xv * E_))[t];
  Ae[(size_t)m * (E_ / 2) + t] = pack_h2(v.x, v.y);
}

// Whh -> MFMA A-fragment layout, f16.
// d8 = panel*2048 + km*64 + lane ; panel = blk*4+w ; km = kt*2+mt
// lane holds A[row = lane&15][k = (lane>>4)*8 + e] of m-tile (panel, mt).
// m-row r = uo*4 + g  (uo=r>>2, g=r&3); unit = blk*32 + (2w+mt)*4 + uo.
__global__ __launch_bounds__(256) void pack_whh_frag(const float* __restrict__ whh,
                                                     unsigned short* __restrict__ out) {
  int d8 = blockIdx.x * 256 + threadIdx.x;   // 0..131071
  int lane  = d8 & 63;
  int km    = (d8 >> 6) & 31;
  int kt    = km >> 1, mt = km & 1;
  int panel = d8 >> 11;                      // 0..63
  int blk = panel >> 2, w = panel & 3;
  int g  = lane & 3;
  int uo = (lane & 15) >> 2;
  int unit = blk * 32 + (2 * w + mt) * 4 + uo;
  int row  = g * 512 + unit;
  int kcol = kt * 32 + (lane >> 4) * 8;
  const float* src = whh + (size_t)row * H_ + kcol;
  float4 a = *(const float4*)(src);
  float4 b = *(const float4*)(src + 4);
  uint4 o;
  o.x = pack_h2(a.x, a.y); o.y = pack_h2(a.z, a.w);
  o.z = pack_h2(b.x, b.y); o.w = pack_h2(b.z, b.w);
  *(uint4*)(out + (size_t)d8 * 8) = o;
}

// hbuf slot 0 <- f16(h0)
__global__ __launch_bounds__(256) void init_h(const float* __restrict__ z,
                                              unsigned short* __restrict__ hbuf) {
  int i = blockIdx.x * 256 + threadIdx.x;    // 0..8191
  int b = i >> 9, u = i & 511;
  hbuf[i] = f16b(z[(size_t)b * 1024 + u]);
}

// ---------- f16 MFMA GEMM: C[M][N] = A[M][K] * Bt[N][K]^T + bias ----------
// PACK=1: write C into the lstm per-lane xg fragment layout instead of [M][N].
template <int PACK>
__global__ __launch_bounds__(256, 2) void gemm_bt(
    const unsigned short* __restrict__ A, const unsigned short* __restrict__ Bt,
    float* __restrict__ C, const float* __restrict__ bias_a,
    const float* __restrict__ bias_b, int M, int N, int K) {
  __shared__ unsigned short As[128 * 32];
  __shared__ unsigned short Bs[128 * 32];
  const int tid = threadIdx.x;
  const int bn = blockIdx.x, bm = blockIdx.y;
  const int lane = tid & 63, wid = tid >> 6;
  const int wr = wid >> 1, wc = wid & 1;
  const int fr = lane & 15, kg = lane >> 4;

  f32x4 acc[4][4] = {};

  const unsigned short* ag = A + (size_t)(bm * 128 + (tid >> 2)) * K + (tid & 3) * 8;
  const unsigned short* bg = Bt + (size_t)(bn * 128 + (tid >> 2)) * K + (tid & 3) * 8;
  char* asl = (char*)As + tid * 16;
  char* bsl = (char*)Bs + tid * 16;

  for (int k0 = 0; k0 < K; k0 += 32) {
    __syncthreads();
    gld_lds16(ag + k0, asl);
    gld_lds16(ag + (size_t)64 * K + k0, asl + 4096);
    gld_lds16(bg + k0, bsl);
    gld_lds16(bg + (size_t)64 * K + k0, bsl + 4096);
    __syncthreads();
    f16x8 aF[4], bF[4];
#pragma unroll
    for (int i = 0; i < 4; ++i)
      aF[i] = *(const f16x8*)&As[(wr * 64 + i * 16 + fr) * 32 + kg * 8];
#pragma unroll
    for (int j = 0; j < 4; ++j)
      bF[j] = *(const f16x8*)&Bs[(wc * 64 + j * 16 + fr) * 32 + kg * 8];
#pragma unroll
    for (int i = 0; i < 4; ++i)
#pragma unroll
      for (int j = 0; j < 4; ++j)
        acc[i][j] = __builtin_amdgcn_mfma_f32_16x16x32_f16(aF[i], bF[j], acc[i][j], 0, 0, 0);
  }

  const int r4 = kg * 4;
#pragma unroll
  for (int j = 0; j < 4; ++j) {
    int col = bn * 128 + wc * 64 + j * 16 + fr;
    float bs = 0.f;
    if (bias_a) bs += bias_a[col];
    if (bias_b) bs += bias_b[col];
#pragma unroll
    for (int i = 0; i < 4; ++i) {
      int row = bm * 128 + wr * 64 + i * 16 + r4;
#pragma unroll
      for (int g = 0; g < 4; ++g) {
        float val = acc[i][j][g] + bs;
        if constexpr (PACK == 0) {
          C[(size_t)(row + g) * N + col] = val;
        } else {
          int rr = row + g;              // = s*16 + batch
          int s = rr >> 4, batch = rr & 15;
          int g4 = col >> 9, unit = col & 511;
          int blk = unit >> 5, ul = unit & 31;
          int w = ul >> 3, mt = (ul >> 2) & 1, uo = ul & 3;
          int lane2 = (uo << 4) | batch;
          size_t d = ((((size_t)s * 16 + blk) * 4 + w) * 64 + lane2) * 8 + mt * 4 + g4;
          C[d] = val;
        }
      }
    }
  }
}

// ---------- LSTM recurrence: 16 blocks x 256 thr, weights VGPR-resident ----------
// Per step: all-wave flag poll -> sc0sc1 stage of h slot -> MFMA from regs ->
// in-lane gates -> publish slice (sc0sc1) + one-shot flag. No fences, no wbl2.
__global__ __launch_bounds__(256, 1) void lstm_coop(
    const float* __restrict__ xgp,          // packed per-lane gate pre-acts
    const unsigned short* __restrict__ whhp,// A-fragment packed weights
    const float* __restrict__ z,            // [B][2H] h0|c0
    unsigned short* __restrict__ hbuf,      // [128][16][512] f16 slots
    uint32_t* __restrict__ flags,           // [128][16] one-shot flags
    float* __restrict__ hs,                 // [B][S][H] f32
    float* __restrict__ hc) {               // [B][2H] h|c (d_out tail)
  const int blk = blockIdx.x, t = threadIdx.x;
  const int w = t >> 6, lane = t & 63;
  const int batch = lane & 15, kgl = lane >> 4;
  const int panel = blk * 4 + w;
  __shared__ alignas(16) unsigned short hlds[8192];   // 16KB swizzled h
  __shared__ alignas(16) unsigned short hpub[512];    // 1KB publish slice

  // resident weights: 32 fragments = 128 VGPRs
  f16x8 A[16][2];
  const unsigned short* wb = whhp + (size_t)panel * 16384 + lane * 8;
#pragma unroll
  for (int kt = 0; kt < 16; ++kt) {
#pragma unroll
    for (int mt = 0; mt < 2; ++mt)
      A[kt][mt] = *(const f16x8*)(wb + (kt * 2 + mt) * 512);
  }

  const int u0 = blk * 32 + (2 * w) * 4 + kgl;   // ul0 = 8w + kgl
  const int u1 = u0 + 4;
  const int ul0 = 8 * w + kgl, ul1 = ul0 + 4;
  float c0 = z[(size_t)batch * 1024 + 512 + u0];
  float c1 = z[(size_t)batch * 1024 + 512 + u1];
  float h0f = 0.f, h1f = 0.f;

  // staging map: thread copies h[sb][sk..sk+32)
  const int sb = t >> 4, sk = (t & 15) * 32;
  const unsigned int sX = (unsigned)(sb & 7) << 4;
  const unsigned int rX = (unsigned)(batch & 7) << 4;
  const unsigned int rbase = batch * 1024 + kgl * 16;
  const unsigned int wbase = sb * 1024 + sk * 2;
  char* lb = (char*)hlds;

  // publish map (threads 0..63): 16B piece q of batch pb
  const int pb = t >> 2, q = t & 3;

#pragma unroll 1
  for (int s = 0; s < S_; ++s) {
    // ---- xg pre-acts (independent, hoisted above poll) ----
    const float* xp = xgp + (((size_t)s * 16 + blk) * 4 + w) * 512 + lane * 8;
    float4 x0 = *(const float4*)(xp);
    float4 x1 = *(const float4*)(xp + 4);

    // ---- wait for slot s (all waves poll; one-shot flags, eq-test) ----
    if (s > 0) {
      const uint32_t* fp = flags + s * 16 + (lane & 15);
      uint32_t fv;
      do {
        asm volatile("global_load_dword %0, %1, off sc0 sc1\n\ts_waitcnt vmcnt(0)"
                     : "=&v"(fv) : "v"(fp) : "memory");
      } while (__ballot(fv != 1u));
    }

    // ---- stage slot s -> LDS (device-coherent loads, swizzled store) ----
    {
      const char* sbase = (const char*)hbuf + (size_t)s * 16384 + sb * 1024 + (t & 15) * 64;
      u32x4 ga, gb, gc, gd;
      asm volatile(
          "global_load_dwordx4 %0, %4, off sc0 sc1\n\t"
          "global_load_dwordx4 %1, %5, off sc0 sc1\n\t"
          "global_load_dwordx4 %2, %6, off sc0 sc1\n\t"
          "global_load_dwordx4 %3, %7, off sc0 sc1\n\t"
          "s_waitcnt vmcnt(0)"
          : "=&v"(ga), "=&v"(gb), "=&v"(gc), "=&v"(gd)
          : "v"(sbase), "v"(sbase + 16), "v"(sbase + 32), "v"(sbase + 48)
          : "memory");
      *(u32x4*)(lb + ((wbase +  0) ^ sX)) = ga;
      *(u32x4*)(lb + ((wbase + 16) ^ sX)) = gb;
      *(u32x4*)(lb + ((wbase + 32) ^ sX)) = gc;
      *(u32x4*)(lb + ((wbase + 48) ^ sX)) = gd;
    }
    __syncthreads();   // hlds ready

    // ---- MFMA: C(128x16) = W_slice @ h^T ----
    f32x4 acc0 = {}, acc1 = {};
#pragma unroll
    for (int kt = 0; kt < 16; ++kt) {
      f16x8 Bf = *(const f16x8*)(lb + ((rbase + kt * 64) ^ rX));
      acc0 = __builtin_amdgcn_mfma_f32_16x16x32_f16(A[kt][0], Bf, acc0, 0, 0, 0);
      acc1 = __builtin_amdgcn_mfma_f32_16x16x32_f16(A[kt][1], Bf, acc1, 0, 0, 0);
    }

    // ---- gates (i,f,g,o in-lane) ----
    float gi0 = acc0[0] + x0.x, gf0 = acc0[1] + x0.y, gg0 = acc0[2] + x0.z, go0 = acc0[3] + x0.w;
    float gi1 = acc1[0] + x1.x, gf1 = acc1[1] + x1.y, gg1 = acc1[2] + x1.z, go1 = acc1[3] + x1.w;
    c0 = sigm(gf0) * c0 + sigm(gi0) * tanh_c(gg0);
    h0f = sigm(go0) * tanh_c(c0);
    c1 = sigm(gf1) * c1 + sigm(gi1) * tanh_c(gg1);
    h1f = sigm(go1) * tanh_c(c1);

    // ---- hs output (normal stores; visible to later dispatches) ----
    float* hr = hs + ((size_t)batch * S_ + s) * H_;
    hr[u0] = h0f;
    hr[u1] = h1f;

    // ---- publish slice to LDS ----
    hpub[batch * 32 + ul0] = f16b(h0f);
    hpub[batch * 32 + ul1] = f16b(h1f);
    __syncthreads();   // hpub ready + hlds consumed

    // ---- wave 0: coherent store of slice + one-shot flag ----
    if (s < S_ - 1 && t < 64) {
      u32x4 v = *(const u32x4*)((const char*)hpub + t * 16);
      char* dst = (char*)hbuf + (size_t)(s + 1) * 16384 + pb * 1024 + blk * 64 + q * 16;
      asm volatile("global_store_dwordx4 %0, %1, off sc0 sc1" :: "v"(dst), "v"(v) : "memory");
      asm volatile("s_waitcnt vmcnt(0)" ::: "memory");
      if (t == 0) {
        uint32_t* fdst = flags + (s + 1) * 16 + blk;
        asm volatile("global_store_dword %0, %1, off sc0 sc1" :: "v"(fdst), "v"(1u) : "memory");
      }
    }
  }

  hc[(size_t)batch * 1024 + u0] = h0f;
  hc[(size_t)batch * 1024 + u1] = h1f;
  hc[(size_t)batch * 1024 + 512 + u0] = c0;
  hc[(size_t)batch * 1024 + 512 + u1] = c1;
}

// ---------- layernorm -> f16 A matrix ----------
__global__ __launch_bounds__(256) void ln_kernel(const float* __restrict__ hs,
                                                 const float* __restrict__ gamma,
                                                 const float* __restrict__ beta,
                                                 uint32_t* __restrict__ Aln) {
  int row = blockIdx.x * 4 + (threadIdx.x >> 6);
  int lane = threadIdx.x & 63;
  const float4* r = (const float4*)(hs + (size_t)row * H_ + lane * 8);
  float4 v0 = r[0], v1 = r[1];
  float s = v0.x + v0.y + v0.z + v0.w + v1.x + v1.y + v1.z + v1.w;
  float q = v0.x * v0.x + v0.y * v0.y + v0.z * v0.z + v0.w * v0.w +
            v1.x * v1.x + v1.y * v1.y + v1.z * v1.z + v1.w * v1.w;
#pragma unroll
  for (int off = 32; off > 0; off >>= 1) {
    s += __shfl_xor(s, off);
    q += __shfl_xor(q, off);
  }
  float mu = s * (1.f / 512.f);
  float var = q * (1.f / 512.f) - mu * mu;
  float rstd = rsqrtf(var + 1e-5f);
  const float4* gp = (const float4*)(gamma + lane * 8);
  const float4* bp = (const float4*)(beta + lane * 8);
  float4 g0 = gp[0], g1 = gp[1], be0 = bp[0], be1 = bp[1];
  float y0 = (v0.x - mu) * rstd * g0.x + be0.x;
  float y1 = (v0.y - mu) * rstd * g0.y + be0.y;
  float y2 = (v0.z - mu) * rstd * g0.z + be0.z;
  float y3 = (v0.w - mu) * rstd * g0.w + be0.w;
  float y4 = (v1.x - mu) * rstd * g1.x + be1.x;
  float y5 = (v1.y - mu) * rstd * g1.y + be1.y;
  float y6 = (v1.z - mu) * rstd * g1.z + be1.z;
  float y7 = (v1.w - mu) * rstd * g1.w + be1.w;
  uint4 o = make_uint4(pack_h2(y0, y1), pack_h2(y2, y3), pack_h2(y4, y5), pack_h2(y6, y7));
  ((uint4*)Aln)[(size_t)row * 64 + lane] = o;
}

// ---------- launch ----------
extern "C" void kernel_launch(void* const* d_in, const int* in_sizes, int n_in,
                              void* d_out, int out_size, void* d_ws, size_t ws_size,
                              hipStream_t stream) {
  const int*   x    = (const int*)d_in[0];
  const float* z    = (const float*)d_in[1];
  const float* emb  = (const float*)d_in[2];
  const float* W_ih = (const float*)d_in[3];
  const float* W_hh = (const float*)d_in[4];
  const float* b_ih = (const float*)d_in[5];
  const float* b_hh = (const float*)d_in[6];
  const float* ln_g = (const float*)d_in[7];
  const float* ln_b = (const float*)d_in[8];
  const float* fc_W = (const float*)d_in[9];
  const float* fc_b = (const float*)d_in[10];
  float* out = (float*)d_out;

  char* ws = (char*)d_ws;
  unsigned short* Ae   = (unsigned short*)(ws + 0);         //  2,097,152 B (reused for hbuf)
  unsigned short* Wih  = (unsigned short*)(ws + 2097152);   //  2,097,152 B (reused for flags)
  unsigned short* Wfc  = (unsigned short*)(ws + 4194304);   // 32,768,000 B
  unsigned short* Whhp = (unsigned short*)(ws + 36962304);  //  2,097,152 B
  float*          xgp  = (float*)(ws + 39059456);           // 16,777,216 B
  float*          hs   = (float*)(ws + 55836672);           //  4,194,304 B
  unsigned short* Aln  = (unsigned short*)(ws + 60030976);  //  2,097,152 B (ends 62,128,128)
  // lstm exchange buffers overlap regions dead after the xg GEMM
  unsigned short* hbuf  = (unsigned short*)(ws + 0);        // 128 slots x 16KB = 2MB
  uint32_t*       flags = (uint32_t*)(ws + 2097152);        // 8KB (in Wih region)

  cvt_f32_f16<<<1024, 256, 0, stream>>>(W_ih, Wih, 262144);
  cvt_f32_f16<<<16000, 256, 0, stream>>>(fc_W, Wfc, 4096000);
  pack_whh_frag<<<512, 256, 0, stream>>>(W_hh, Whhp);
  gather_embed<<<2048, 256, 0, stream>>>(x, emb, (uint32_t*)Ae);

  // xg packed: xgp[lane-fragment layout] = e . W_ih[g] + b_ih + b_hh
  gemm_bt<1><<<dim3(16, 16), 256, 0, stream>>>(Ae, Wih, xgp, b_ih, b_hh, 2048, 2048, 512);

  init_h<<<32, 256, 0, stream>>>(z, hbuf);
  lstm_coop<<<16, 256, 0, stream>>>(xgp, Whhp, z, hbuf, flags, hs, out + (size_t)65536000);

  ln_kernel<<<512, 256, 0, stream>>>(hs, ln_g, ln_b, (uint32_t*)Aln);

  // logits[b*128+s][v] = ln . fc_W[v] + fc_b
  gemm_bt<0><<<dim3(250, 16), 256, 0, stream>>>(Aln, Wfc, out, fc_b, nullptr, 2048, 32000, 512);
}